// Round 3
// baseline (920.442 us; speedup 1.0000x reference)
//
#include <hip/hip_runtime.h>
#include <math.h>

#define NN 4
#define CCH 256
#define LLEN 4096
#define CR 64
#define NHEAD 4
#define NHL 16384      // NHEAD * LLEN
#define NBINS 67       // code values 0..66 (bucket 0..63 + head 0..3)

__device__ __forceinline__ float4 f4fma(float4 a, float4 b, float4 c) {
  c.x = fmaf(a.x, b.x, c.x);
  c.y = fmaf(a.y, b.y, c.y);
  c.z = fmaf(a.z, b.z, c.z);
  c.w = fmaf(a.w, b.w, c.w);
  return c;
}
__device__ __forceinline__ float4 f4fmas(float s, float4 b, float4 c) {
  c.x = fmaf(s, b.x, c.x);
  c.y = fmaf(s, b.y, c.y);
  c.z = fmaf(s, b.z, c.z);
  c.w = fmaf(s, b.w, c.w);
  return c;
}

// ---------------- conv_match: [N,C,L] -> BN1 -> ReLU -> xe [N,L,64] ----------------
__global__ __launch_bounds__(256) void k_conv_match(
    const float* __restrict__ x, const float* __restrict__ w,
    const float* __restrict__ g, const float* __restrict__ b,
    const float* __restrict__ m, const float* __restrict__ v,
    float* __restrict__ xe) {
  __shared__ float xs[256 * 68];   // [ci][66 used, stride 68]
  __shared__ float wl[64 * 193];   // [co][192 used, stride 193]
  const int tid = threadIdx.x;
  const int n = blockIdx.x >> 6;
  const int l0 = (blockIdx.x & 63) << 6;
  const float* xn = x + (size_t)n * CCH * LLEN;
  for (int idx = tid; idx < 256 * 66; idx += 256) {
    int ci = idx / 66, j = idx - ci * 66;
    int l = l0 + j - 1;
    xs[ci * 68 + j] = (l >= 0 && l < LLEN) ? xn[ci * LLEN + l] : 0.f;
  }
  const int co = tid & 63;
  const int dlg = tid >> 6;   // dl = dlg*16 + q
  float acc[16];
#pragma unroll
  for (int q = 0; q < 16; ++q) acc[q] = 0.f;
  for (int cc = 0; cc < 4; ++cc) {
    __syncthreads();
    for (int idx = tid; idx < 12288; idx += 256) {
      int cw = idx / 192, r = idx - cw * 192;
      wl[cw * 193 + r] = w[cw * 768 + cc * 192 + r];
    }
    __syncthreads();
    const float* wbase = &wl[co * 193];
    for (int cil = 0; cil < 64; ++cil) {
      const float* xrow = &xs[(cc * 64 + cil) * 68 + dlg * 16];
      float4 p0 = ((const float4*)xrow)[0];
      float4 p1 = ((const float4*)xrow)[1];
      float4 p2 = ((const float4*)xrow)[2];
      float4 p3 = ((const float4*)xrow)[3];
      float4 p4 = ((const float4*)xrow)[4];
      float xr[20] = {p0.x,p0.y,p0.z,p0.w, p1.x,p1.y,p1.z,p1.w,
                      p2.x,p2.y,p2.z,p2.w, p3.x,p3.y,p3.z,p3.w,
                      p4.x,p4.y,p4.z,p4.w};
      float w0 = wbase[cil*3], w1 = wbase[cil*3+1], w2 = wbase[cil*3+2];
#pragma unroll
      for (int q = 0; q < 16; ++q) {
        acc[q] = fmaf(w0, xr[q], acc[q]);
        acc[q] = fmaf(w1, xr[q+1], acc[q]);
        acc[q] = fmaf(w2, xr[q+2], acc[q]);
      }
    }
  }
  float scale = g[co] * rsqrtf(v[co] + 1e-5f);
  float bias = b[co] - m[co] * scale;
  float* xo = xe + ((size_t)n * LLEN + l0) * 64 + co;
#pragma unroll
  for (int q = 0; q < 16; ++q) {
    float val = acc[q] * scale + bias;
    xo[(dlg * 16 + q) * 64] = val > 0.f ? val : 0.f;
  }
}

// ---------------- conv_asm (1x1): [N,C,L] -> BN2 -> ReLU -> ye [N,L,256] ----------------
__global__ __launch_bounds__(256) void k_conv_asm(
    const float* __restrict__ x, const float* __restrict__ w,
    const float* __restrict__ g, const float* __restrict__ b,
    const float* __restrict__ m, const float* __restrict__ v,
    float* __restrict__ ye) {
  __shared__ float xt[64 * 68];        // [ci][l], stride 68
  __shared__ float wt[2 * 64 * 132];   // [parity][ci][132], quad-interleaved over c
  const int tid = threadIdx.x;
  const int n = blockIdx.x >> 6;
  const int l0 = (blockIdx.x & 63) << 6;
  const int cg = tid & 31, lt = tid >> 5;   // c0 = cg*8, l = l0 + lt*8 + q
  float4 a0[8], a1[8];
#pragma unroll
  for (int q = 0; q < 8; ++q) { a0[q] = make_float4(0,0,0,0); a1[q] = make_float4(0,0,0,0); }
  for (int cc = 0; cc < 4; ++cc) {
    __syncthreads();
    for (int idx = tid; idx < 4096; idx += 256) {
      int ci = idx >> 6, dl = idx & 63;
      xt[ci * 68 + dl] = x[((size_t)n * 256 + cc * 64 + ci) * 4096 + l0 + dl];
    }
    for (int idx = tid; idx < 16384; idx += 256) {
      int ci = idx & 63, c = idx >> 6;
      int qd = c >> 2;
      int par = qd & 1, qh = qd >> 1, wq = c & 3;
      wt[par * 8448 + ci * 132 + qh * 4 + wq] = w[c * 256 + cc * 64 + ci];
    }
    __syncthreads();
    for (int ci = 0; ci < 64; ++ci) {
      const float4 xv0 = *(const float4*)&xt[ci * 68 + lt * 8];
      const float4 xv1 = *(const float4*)&xt[ci * 68 + lt * 8 + 4];
      const float4 w0 = *(const float4*)&wt[ci * 132 + cg * 4];          // c = 8cg..8cg+3
      const float4 w1 = *(const float4*)&wt[8448 + ci * 132 + cg * 4];   // c = 8cg+4..8cg+7
      float xl[8] = {xv0.x, xv0.y, xv0.z, xv0.w, xv1.x, xv1.y, xv1.z, xv1.w};
#pragma unroll
      for (int q = 0; q < 8; ++q) {
        a0[q] = f4fmas(xl[q], w0, a0[q]);
        a1[q] = f4fmas(xl[q], w1, a1[q]);
      }
    }
  }
  const int c0 = cg * 8;
  float sc[8], bs[8];
#pragma unroll
  for (int u = 0; u < 8; ++u) {
    float s = g[c0+u] * rsqrtf(v[c0+u] + 1e-5f);
    sc[u] = s; bs[u] = b[c0+u] - m[c0+u] * s;
  }
#pragma unroll
  for (int q = 0; q < 8; ++q) {
    int l = l0 + lt * 8 + q;
    float4 o0, o1;
    o0.x = fmaxf(a0[q].x*sc[0]+bs[0], 0.f);
    o0.y = fmaxf(a0[q].y*sc[1]+bs[1], 0.f);
    o0.z = fmaxf(a0[q].z*sc[2]+bs[2], 0.f);
    o0.w = fmaxf(a0[q].w*sc[3]+bs[3], 0.f);
    o1.x = fmaxf(a1[q].x*sc[4]+bs[4], 0.f);
    o1.y = fmaxf(a1[q].y*sc[5]+bs[5], 0.f);
    o1.z = fmaxf(a1[q].z*sc[6]+bs[6], 0.f);
    o1.w = fmaxf(a1[q].w*sc[7]+bs[7], 0.f);
    float4* dst = (float4*)(ye + ((size_t)n * LLEN + l) * 256 + c0);
    dst[0] = o0; dst[1] = o1;
  }
}

// ---------------- LSH codes: rv = xe @ rot, argmax over [rv, -rv], +h ----------------
__global__ __launch_bounds__(256) void k_codes(
    const float* __restrict__ xe, const float* __restrict__ rot,
    int* __restrict__ codes) {
  __shared__ float xsh[64 * 65];
  const int tid = threadIdx.x;
  const int n = blockIdx.x >> 6;
  const int t0 = (blockIdx.x & 63) << 6;
  for (int idx = tid; idx < 4096; idx += 256) {
    int tt = idx >> 6, f = idx & 63;
    xsh[tt * 65 + f] = xe[((size_t)n * LLEN + t0 + tt) * 64 + f];
  }
  __syncthreads();
  const int tt = tid & 63, h = tid >> 6;
  float rvv[32];
#pragma unroll
  for (int i = 0; i < 32; ++i) rvv[i] = 0.f;
  const float* xr = &xsh[tt * 65];
  for (int f = 0; f < 64; ++f) {
    float xf = xr[f];
    const float* rr = rot + ((f << 2) + h) * 32;   // rot[f][h][i]
#pragma unroll
    for (int i = 0; i < 32; ++i) rvv[i] = fmaf(xf, rr[i], rvv[i]);
  }
  // argmax over concat([rv, -rv]) with first-occurrence tie semantics
  float best = rvv[0]; int bi = 0;
#pragma unroll
  for (int i = 1; i < 32; ++i) { if (rvv[i] > best) { best = rvv[i]; bi = i; } }
#pragma unroll
  for (int i = 0; i < 32; ++i) { float nv = -rvv[i]; if (nv > best) { best = nv; bi = 32 + i; } }
  codes[n * NHL + h * LLEN + t0 + tt] = bi + h;
}

// ---------------- counting sort: histogram + exclusive scan ----------------
__global__ __launch_bounds__(256) void k_hist(const int* __restrict__ codes,
                                              int* __restrict__ offs) {
  __shared__ int hist[NBINS];
  const int tid = threadIdx.x;
  const int n = blockIdx.x;
  if (tid < NBINS) hist[tid] = 0;
  __syncthreads();
  const int* cp = codes + n * NHL;
  for (int idx = tid; idx < NHL; idx += 256) atomicAdd(&hist[cp[idx]], 1);
  __syncthreads();
  if (tid == 0) {
    int s = 0;
    for (int c = 0; c < NBINS; ++c) { offs[n * (NBINS + 1) + c] = s; s += hist[c]; }
    offs[n * (NBINS + 1) + NBINS] = s;
  }
}

// stable scatter: one wave per (n, code); ballot + prefix popcount preserves order
__global__ __launch_bounds__(64) void k_scatter(const int* __restrict__ codes,
                                                const int* __restrict__ offs,
                                                int* __restrict__ sidx) {
  const int n = blockIdx.x / NBINS;
  const int c = blockIdx.x - n * NBINS;
  const int lane = threadIdx.x;
  const int* cp = codes + n * NHL;
  int base = offs[n * (NBINS + 1) + c];
  for (int ch = 0; ch < NHL / 64; ++ch) {
    int j = (ch << 6) + lane;
    int cv = cp[j];
    unsigned long long mk = __ballot(cv == c);
    if (cv == c) {
      int pos = base + __popcll(mk & ((1ull << lane) - 1ull));
      sidx[n * NHL + pos] = j;
    }
    base += __popcll(mk);
  }
}

// ---------------- lse pass: per (n,h,k) chunk, raw = xb @ xm^T, lse over 192 ----------------
__global__ __launch_bounds__(256) void k_lse(const float* __restrict__ xe,
                                             const int* __restrict__ sidx,
                                             float* __restrict__ lse) {
  __shared__ float xall[192 * 68];
  __shared__ float rinv[192];
  __shared__ int tmap[192];
  __shared__ float pm[256], ps[256];
  const int tid = threadIdx.x;
  const int blk = blockIdx.x;
  const int n = blk >> 8, h = (blk >> 6) & 3, k = blk & 63;
  if (tid < 192) {
    int jl = tid & 63;
    int chn = (tid < 64) ? k : ((tid < 128) ? ((k + 63) & 63) : ((k + 1) & 63));
    tmap[tid] = sidx[n * NHL + h * LLEN + chn * 64 + jl] & (LLEN - 1);
  }
  __syncthreads();
  const float* xen = xe + (size_t)n * LLEN * 64;
  for (int idx = tid; idx < 192 * 64; idx += 256) {
    int r = idx >> 6, f = idx & 63;
    xall[r * 68 + f] = xen[(size_t)tmap[r] * 64 + f];
  }
  __syncthreads();
  if (tid < 192) {
    const float* row = &xall[tid * 68];
    float s = 0.f;
    for (int f = 0; f < 64; ++f) { float vv = row[f]; s = fmaf(vv, vv, s); }
    rinv[tid] = 1.f / fmaxf(sqrtf(s), 5e-5f);
  }
  __syncthreads();
  const int il = tid & 63, jg = tid >> 6;
  float4 xi[16];
  {
    const float4* xr = (const float4*)&xall[il * 68];
#pragma unroll
    for (int u = 0; u < 16; ++u) xi[u] = xr[u];
  }
  float ml = -1e30f, sl = 0.f;
  for (int j = jg * 48; j < jg * 48 + 48; ++j) {
    const float4* xj = (const float4*)&xall[j * 68];
    float4 d4 = make_float4(0, 0, 0, 0);
#pragma unroll
    for (int u = 0; u < 16; ++u) d4 = f4fma(xi[u], xj[u], d4);
    float d = (d4.x + d4.y + d4.z + d4.w) * rinv[j];
    if (d > ml) { sl = sl * expf(ml - d) + 1.f; ml = d; }
    else sl += expf(d - ml);
  }
  pm[il * 4 + jg] = ml; ps[il * 4 + jg] = sl;
  __syncthreads();
  if (tid < 64) {
    float m0 = pm[tid*4], m1 = pm[tid*4+1], m2 = pm[tid*4+2], m3 = pm[tid*4+3];
    float mm = fmaxf(fmaxf(m0, m1), fmaxf(m2, m3));
    float ss = ps[tid*4]  * expf(m0 - mm) + ps[tid*4+1] * expf(m1 - mm)
             + ps[tid*4+2] * expf(m2 - mm) + ps[tid*4+3] * expf(m3 - mm);
    lse[n * NHL + h * LLEN + k * 64 + tid] = mm + logf(ss);
  }
}

// ---------------- att pass: score = exp(raw - lse); att = score @ yb3; scatter+weight ----------------
__global__ __launch_bounds__(256) void k_att(const float* __restrict__ xe,
                                             const float* __restrict__ ye,
                                             const int* __restrict__ sidx,
                                             const float* __restrict__ lse,
                                             float* __restrict__ accb) {
  __shared__ float score[64 * 196];
  __shared__ float reg2[16640];   // phase1: xall[192*68]; phase2: yc[64*260]
  __shared__ float rinv[192];
  __shared__ int tmap[192];
  __shared__ float pw[64];
  __shared__ int dl0[64];
  const int tid = threadIdx.x;
  const int blk = blockIdx.x;
  const int n = blk >> 8, h = (blk >> 6) & 3, k = blk & 63;
  if (tid < 192) {
    int jl = tid & 63;
    int chn = (tid < 64) ? k : ((tid < 128) ? ((k + 63) & 63) : ((k + 1) & 63));
    tmap[tid] = sidx[n * NHL + h * LLEN + chn * 64 + jl] & (LLEN - 1);
  }
  if (tid < 64) {
    int i0 = sidx[n * NHL + h * LLEN + k * 64 + tid];
    int h0 = i0 >> 12, l0v = i0 & (LLEN - 1);
    float e0 = lse[n * NHL + l0v];
    float e1 = lse[n * NHL + LLEN + l0v];
    float e2 = lse[n * NHL + 2 * LLEN + l0v];
    float e3 = lse[n * NHL + 3 * LLEN + l0v];
    float mx = fmaxf(fmaxf(e0, e1), fmaxf(e2, e3));
    float x0 = expf(e0 - mx), x1 = expf(e1 - mx), x2 = expf(e2 - mx), x3 = expf(e3 - mx);
    float sum = x0 + x1 + x2 + x3;
    float eh = (h0 == 0) ? x0 : (h0 == 1) ? x1 : (h0 == 2) ? x2 : x3;
    pw[tid] = eh / sum;
    dl0[tid] = l0v;
  }
  __syncthreads();
  const float* xen = xe + (size_t)n * LLEN * 64;
  for (int idx = tid; idx < 192 * 64; idx += 256) {
    int r = idx >> 6, f = idx & 63;
    reg2[r * 68 + f] = xen[(size_t)tmap[r] * 64 + f];
  }
  __syncthreads();
  if (tid < 192) {
    const float* row = &reg2[tid * 68];
    float s = 0.f;
    for (int f = 0; f < 64; ++f) { float vv = row[f]; s = fmaf(vv, vv, s); }
    rinv[tid] = 1.f / fmaxf(sqrtf(s), 5e-5f);
  }
  __syncthreads();
  {
    const int il = tid & 63, jg = tid >> 6;
    float4 xi[16];
    const float4* xr = (const float4*)&reg2[il * 68];
#pragma unroll
    for (int u = 0; u < 16; ++u) xi[u] = xr[u];
    float lse_i = lse[n * NHL + h * LLEN + k * 64 + il];
    for (int j = jg * 48; j < jg * 48 + 48; ++j) {
      const float4* xj = (const float4*)&reg2[j * 68];
      float4 d4 = make_float4(0, 0, 0, 0);
#pragma unroll
      for (int u = 0; u < 16; ++u) d4 = f4fma(xi[u], xj[u], d4);
      float d = (d4.x + d4.y + d4.z + d4.w) * rinv[j];
      score[il * 196 + j] = expf(d - lse_i);
    }
  }
  const int it = tid >> 5, cg = tid & 31;   // rows i = q*8 + it, cols c = cg*8..cg*8+7
  float4 a0[8], a1[8];
#pragma unroll
  for (int q = 0; q < 8; ++q) { a0[q] = make_float4(0,0,0,0); a1[q] = make_float4(0,0,0,0); }
  for (int jc = 0; jc < 3; ++jc) {
    __syncthreads();   // phase1 reads of reg2 done (jc=0); prev chunk compute done (jc>0)
    {
      int r = tid >> 2, qd = tid & 3;
      int t = tmap[jc * 64 + r];
      const float4* ysrc = (const float4*)(ye + ((size_t)n * LLEN + t) * 256 + qd * 64);
      float4* ydst = (float4*)&reg2[r * 260 + qd * 64];
#pragma unroll
      for (int u = 0; u < 16; ++u) ydst[u] = ysrc[u];
    }
    __syncthreads();
    for (int jj = 0; jj < 64; ++jj) {
      int jl = (jj + it * 4) & 63;    // rotate rows per it-group to spread LDS banks
      int j = jc * 64 + jl;
      const float4* yr = (const float4*)&reg2[jl * 260];
      float4 y0 = yr[cg * 2], y1 = yr[cg * 2 + 1];
#pragma unroll
      for (int q = 0; q < 8; ++q) {
        float s = score[(q * 8 + it) * 196 + j];
        a0[q] = f4fmas(s, y0, a0[q]);
        a1[q] = f4fmas(s, y1, a1[q]);
      }
    }
  }
#pragma unroll
  for (int q = 0; q < 8; ++q) {
    const int i = q * 8 + it;
    float p = pw[i];
    float* dst = accb + ((size_t)n * LLEN + dl0[i]) * 256 + cg * 8;
    atomicAdd(dst + 0, a0[q].x * p);
    atomicAdd(dst + 1, a0[q].y * p);
    atomicAdd(dst + 2, a0[q].z * p);
    atomicAdd(dst + 3, a0[q].w * p);
    atomicAdd(dst + 4, a1[q].x * p);
    atomicAdd(dst + 5, a1[q].y * p);
    atomicAdd(dst + 6, a1[q].z * p);
    atomicAdd(dst + 7, a1[q].w * p);
  }
}

// ---------------- final: transpose [N,L,C]->[N,C,L], BN3, + residual ----------------
__global__ __launch_bounds__(256) void k_final(const float* __restrict__ acc,
                                               const float* __restrict__ x,
                                               const float* __restrict__ g,
                                               const float* __restrict__ b,
                                               const float* __restrict__ m,
                                               const float* __restrict__ v,
                                               float* __restrict__ out) {
  __shared__ float t[64 * 65];
  const int tid = threadIdx.x;
  const int blk = blockIdx.x;
  const int n = blk >> 8, lt = (blk >> 2) & 63, ct = blk & 3;
  const int l0 = lt << 6, c0 = ct << 6;
  for (int idx = tid; idx < 4096; idx += 256) {
    int dl = idx >> 6, dc = idx & 63;
    t[dl * 65 + dc] = acc[((size_t)n * LLEN + l0 + dl) * 256 + c0 + dc];
  }
  __syncthreads();
  for (int idx = tid; idx < 4096; idx += 256) {
    int dc = idx >> 6, dl = idx & 63;
    int c = c0 + dc;
    float s = g[c] * rsqrtf(v[c] + 1e-5f);
    float bias = b[c] - m[c] * s;
    size_t o = ((size_t)n * 256 + c) * LLEN + l0 + dl;
    out[o] = t[dl * 65 + dc] * s + bias + x[o];
  }
}

extern "C" void kernel_launch(void* const* d_in, const int* in_sizes, int n_in,
                              void* d_out, int out_size, void* d_ws, size_t ws_size,
                              hipStream_t stream) {
  const float* x       = (const float*)d_in[0];
  const float* rot     = (const float*)d_in[1];
  const float* w_match = (const float*)d_in[2];
  const float* bn1_g   = (const float*)d_in[3];
  const float* bn1_b   = (const float*)d_in[4];
  const float* bn1_m   = (const float*)d_in[5];
  const float* bn1_v   = (const float*)d_in[6];
  const float* w_asm   = (const float*)d_in[7];
  const float* bn2_g   = (const float*)d_in[8];
  const float* bn2_b   = (const float*)d_in[9];
  const float* bn2_m   = (const float*)d_in[10];
  const float* bn2_v   = (const float*)d_in[11];
  const float* bn3_g   = (const float*)d_in[12];
  const float* bn3_b   = (const float*)d_in[13];
  const float* bn3_m   = (const float*)d_in[14];
  const float* bn3_v   = (const float*)d_in[15];
  float* out = (float*)d_out;

  float* ws   = (float*)d_ws;
  float* xe   = ws;                    // [4][4096][64]   = 1,048,576 f
  float* ye   = xe + 1048576;          // [4][4096][256]  = 4,194,304 f
  float* acc  = ye + 4194304;          // [4][4096][256]  = 4,194,304 f
  float* lse  = acc + 4194304;         // [4][16384]      = 65,536 f
  int* codes  = (int*)(lse + 65536);   // [4][16384]
  int* sidx   = codes + 65536;         // [4][16384]
  int* offs   = sidx + 65536;          // [4][68]
  // total ~38.3 MB of d_ws

  hipMemsetAsync(acc, 0, (size_t)4194304 * sizeof(float), stream);
  k_conv_match<<<256, 256, 0, stream>>>(x, w_match, bn1_g, bn1_b, bn1_m, bn1_v, xe);
  k_conv_asm<<<256, 256, 0, stream>>>(x, w_asm, bn2_g, bn2_b, bn2_m, bn2_v, ye);
  k_codes<<<256, 256, 0, stream>>>(xe, rot, codes);
  k_hist<<<NN, 256, 0, stream>>>(codes, offs);
  k_scatter<<<NN * NBINS, 64, 0, stream>>>(codes, offs, sidx);
  k_lse<<<1024, 256, 0, stream>>>(xe, sidx, lse);
  k_att<<<1024, 256, 0, stream>>>(xe, ye, sidx, lse, acc);
  k_final<<<1024, 256, 0, stream>>>(acc, x, bn3_g, bn3_b, bn3_m, bn3_v, out);
}

// Round 6
// 491.571 us; speedup vs baseline: 1.8725x; 1.8725x over previous
//
#include <hip/hip_runtime.h>
#include <math.h>

#define NN 4
#define CCH 256
#define LLEN 4096
#define NHEAD 4
#define NHL 16384      // NHEAD * LLEN
#define NBINS 67       // code values 0..66 (bucket 0..63 + head 0..3)

__device__ __forceinline__ float4 f4fma(float4 a, float4 b, float4 c) {
  c.x = fmaf(a.x, b.x, c.x);
  c.y = fmaf(a.y, b.y, c.y);
  c.z = fmaf(a.z, b.z, c.z);
  c.w = fmaf(a.w, b.w, c.w);
  return c;
}
__device__ __forceinline__ float4 f4fmas(float s, float4 b, float4 c) {
  c.x = fmaf(s, b.x, c.x);
  c.y = fmaf(s, b.y, c.y);
  c.z = fmaf(s, b.z, c.z);
  c.w = fmaf(s, b.w, c.w);
  return c;
}

// ---------------- conv_match: [N,C,L] -> BN1 -> ReLU -> xe [N,L,64] ----------------
__global__ __launch_bounds__(256) void k_conv_match(
    const float* __restrict__ x, const float* __restrict__ w,
    const float* __restrict__ g, const float* __restrict__ b,
    const float* __restrict__ m, const float* __restrict__ v,
    float* __restrict__ xe) {
  __shared__ float xs[256 * 68];   // [ci][66 used, stride 68]
  __shared__ float wl[64 * 193];   // [co][192 used, stride 193]
  const int tid = threadIdx.x;
  const int n = blockIdx.x >> 6;
  const int l0 = (blockIdx.x & 63) << 6;
  const float* xn = x + (size_t)n * CCH * LLEN;
  for (int idx = tid; idx < 256 * 66; idx += 256) {
    int ci = idx / 66, j = idx - ci * 66;
    int l = l0 + j - 1;
    xs[ci * 68 + j] = (l >= 0 && l < LLEN) ? xn[ci * LLEN + l] : 0.f;
  }
  const int co = tid & 63;
  const int dlg = tid >> 6;   // dl = dlg*16 + q
  float acc[16];
#pragma unroll
  for (int q = 0; q < 16; ++q) acc[q] = 0.f;
  for (int cc = 0; cc < 4; ++cc) {
    __syncthreads();
    for (int idx = tid; idx < 12288; idx += 256) {
      int cw = idx / 192, r = idx - cw * 192;
      wl[cw * 193 + r] = w[cw * 768 + cc * 192 + r];
    }
    __syncthreads();
    const float* wbase = &wl[co * 193];
    for (int cil = 0; cil < 64; ++cil) {
      const float* xrow = &xs[(cc * 64 + cil) * 68 + dlg * 16];
      float4 p0 = ((const float4*)xrow)[0];
      float4 p1 = ((const float4*)xrow)[1];
      float4 p2 = ((const float4*)xrow)[2];
      float4 p3 = ((const float4*)xrow)[3];
      float4 p4 = ((const float4*)xrow)[4];
      float xr[20] = {p0.x,p0.y,p0.z,p0.w, p1.x,p1.y,p1.z,p1.w,
                      p2.x,p2.y,p2.z,p2.w, p3.x,p3.y,p3.z,p3.w,
                      p4.x,p4.y,p4.z,p4.w};
      float w0 = wbase[cil*3], w1 = wbase[cil*3+1], w2 = wbase[cil*3+2];
#pragma unroll
      for (int q = 0; q < 16; ++q) {
        acc[q] = fmaf(w0, xr[q], acc[q]);
        acc[q] = fmaf(w1, xr[q+1], acc[q]);
        acc[q] = fmaf(w2, xr[q+2], acc[q]);
      }
    }
  }
  float scale = g[co] * rsqrtf(v[co] + 1e-5f);
  float bias = b[co] - m[co] * scale;
  float* xo = xe + ((size_t)n * LLEN + l0) * 64 + co;
#pragma unroll
  for (int q = 0; q < 16; ++q) {
    float val = acc[q] * scale + bias;
    xo[(dlg * 16 + q) * 64] = val > 0.f ? val : 0.f;
  }
}

// ---------------- conv_asm (1x1): [N,C,L] -> BN2 -> ReLU -> ye [N,L,256] ----------------
__global__ __launch_bounds__(256) void k_conv_asm(
    const float* __restrict__ x, const float* __restrict__ w,
    const float* __restrict__ g, const float* __restrict__ b,
    const float* __restrict__ m, const float* __restrict__ v,
    float* __restrict__ ye) {
  __shared__ float xt[64 * 68];        // [ci][l], stride 68
  __shared__ float wt[2 * 64 * 132];   // [parity][ci][132], quad-interleaved over c
  const int tid = threadIdx.x;
  const int n = blockIdx.x >> 6;
  const int l0 = (blockIdx.x & 63) << 6;
  const int cg = tid & 31, lt = tid >> 5;   // c0 = cg*8, l = l0 + lt*8 + q
  float4 a0[8], a1[8];
#pragma unroll
  for (int q = 0; q < 8; ++q) { a0[q] = make_float4(0,0,0,0); a1[q] = make_float4(0,0,0,0); }
  for (int cc = 0; cc < 4; ++cc) {
    __syncthreads();
    for (int idx = tid; idx < 4096; idx += 256) {
      int ci = idx >> 6, dl = idx & 63;
      xt[ci * 68 + dl] = x[((size_t)n * 256 + cc * 64 + ci) * 4096 + l0 + dl];
    }
    for (int idx = tid; idx < 16384; idx += 256) {
      int ci = idx & 63, c = idx >> 6;
      int qd = c >> 2;
      int par = qd & 1, qh = qd >> 1, wq = c & 3;
      wt[par * 8448 + ci * 132 + qh * 4 + wq] = w[c * 256 + cc * 64 + ci];
    }
    __syncthreads();
    for (int ci = 0; ci < 64; ++ci) {
      const float4 xv0 = *(const float4*)&xt[ci * 68 + lt * 8];
      const float4 xv1 = *(const float4*)&xt[ci * 68 + lt * 8 + 4];
      const float4 w0 = *(const float4*)&wt[ci * 132 + cg * 4];          // c = 8cg..8cg+3
      const float4 w1 = *(const float4*)&wt[8448 + ci * 132 + cg * 4];   // c = 8cg+4..8cg+7
      float xl[8] = {xv0.x, xv0.y, xv0.z, xv0.w, xv1.x, xv1.y, xv1.z, xv1.w};
#pragma unroll
      for (int q = 0; q < 8; ++q) {
        a0[q] = f4fmas(xl[q], w0, a0[q]);
        a1[q] = f4fmas(xl[q], w1, a1[q]);
      }
    }
  }
  const int c0 = cg * 8;
  float sc[8], bs[8];
#pragma unroll
  for (int u = 0; u < 8; ++u) {
    float s = g[c0+u] * rsqrtf(v[c0+u] + 1e-5f);
    sc[u] = s; bs[u] = b[c0+u] - m[c0+u] * s;
  }
#pragma unroll
  for (int q = 0; q < 8; ++q) {
    int l = l0 + lt * 8 + q;
    float4 o0, o1;
    o0.x = fmaxf(a0[q].x*sc[0]+bs[0], 0.f);
    o0.y = fmaxf(a0[q].y*sc[1]+bs[1], 0.f);
    o0.z = fmaxf(a0[q].z*sc[2]+bs[2], 0.f);
    o0.w = fmaxf(a0[q].w*sc[3]+bs[3], 0.f);
    o1.x = fmaxf(a1[q].x*sc[4]+bs[4], 0.f);
    o1.y = fmaxf(a1[q].y*sc[5]+bs[5], 0.f);
    o1.z = fmaxf(a1[q].z*sc[6]+bs[6], 0.f);
    o1.w = fmaxf(a1[q].w*sc[7]+bs[7], 0.f);
    float4* dst = (float4*)(ye + ((size_t)n * LLEN + l) * 256 + c0);
    dst[0] = o0; dst[1] = o1;
  }
}

// ---------------- LSH codes: rv = xe @ rot, argmax over [rv, -rv], +h ----------------
__global__ __launch_bounds__(256) void k_codes(
    const float* __restrict__ xe, const float* __restrict__ rot,
    int* __restrict__ codes) {
  __shared__ float xsh[64 * 65];
  const int tid = threadIdx.x;
  const int n = blockIdx.x >> 6;
  const int t0 = (blockIdx.x & 63) << 6;
  for (int idx = tid; idx < 4096; idx += 256) {
    int tt = idx >> 6, f = idx & 63;
    xsh[tt * 65 + f] = xe[((size_t)n * LLEN + t0 + tt) * 64 + f];
  }
  __syncthreads();
  const int tt = tid & 63, h = tid >> 6;
  float rvv[32];
#pragma unroll
  for (int i = 0; i < 32; ++i) rvv[i] = 0.f;
  const float* xr = &xsh[tt * 65];
  for (int f = 0; f < 64; ++f) {
    float xf = xr[f];
    const float* rr = rot + ((f << 2) + h) * 32;   // rot[f][h][i]
#pragma unroll
    for (int i = 0; i < 32; ++i) rvv[i] = fmaf(xf, rr[i], rvv[i]);
  }
  float best = rvv[0]; int bi = 0;
#pragma unroll
  for (int i = 1; i < 32; ++i) { if (rvv[i] > best) { best = rvv[i]; bi = i; } }
#pragma unroll
  for (int i = 0; i < 32; ++i) { float nv = -rvv[i]; if (nv > best) { best = nv; bi = 32 + i; } }
  codes[n * NHL + h * LLEN + t0 + tt] = bi + h;
}

// ---------------- counting sort: histogram + exclusive scan ----------------
__global__ __launch_bounds__(256) void k_hist(const int* __restrict__ codes,
                                              int* __restrict__ offs) {
  __shared__ int hist[NBINS];
  const int tid = threadIdx.x;
  const int n = blockIdx.x;
  if (tid < NBINS) hist[tid] = 0;
  __syncthreads();
  const int* cp = codes + n * NHL;
  for (int idx = tid; idx < NHL; idx += 256) atomicAdd(&hist[cp[idx]], 1);
  __syncthreads();
  if (tid == 0) {
    int s = 0;
    for (int c = 0; c < NBINS; ++c) { offs[n * (NBINS + 1) + c] = s; s += hist[c]; }
    offs[n * (NBINS + 1) + NBINS] = s;
  }
}

// stable scatter: one wave per (n, code); also writes the inverse permutation
__global__ __launch_bounds__(64) void k_scatter(const int* __restrict__ codes,
                                                const int* __restrict__ offs,
                                                int* __restrict__ sidx,
                                                int* __restrict__ undo) {
  const int n = blockIdx.x / NBINS;
  const int c = blockIdx.x - n * NBINS;
  const int lane = threadIdx.x;
  const int* cp = codes + n * NHL;
  int base = offs[n * (NBINS + 1) + c];
  for (int ch = 0; ch < NHL / 64; ++ch) {
    int j = (ch << 6) + lane;
    int cv = cp[j];
    unsigned long long mk = __ballot(cv == c);
    if (cv == c) {
      int pos = base + __popcll(mk & ((1ull << lane) - 1ull));
      sidx[n * NHL + pos] = j;
      undo[n * NHL + j] = pos;
    }
    base += __popcll(mk);
  }
}

// ---------------- fused attention: QK^T + lse + softmax + PV, contiguous writes ----------------
// block = (n, h, k); writes att[n][h*L + k*64 + i][c] (softmax-normalized) and lse[n][p].
__global__ __launch_bounds__(256, 2) void k_att2(const float* __restrict__ xe,
                                                 const float* __restrict__ ye,
                                                 const int* __restrict__ sidx,
                                                 float* __restrict__ lseg,
                                                 float* __restrict__ att) {
  __shared__ float score[64 * 193];   // stride 193: (il+j)%32 -> conflict-free
  __shared__ float stg[4352];         // xtile[64][68] (QK) then ytile[16][260] (PV)
  __shared__ int   tmap[192];
  __shared__ float rinv_c[64];
  __shared__ float psum[256];
  __shared__ float pm[256], ps[256];
  __shared__ float lse_row[64];
  const int tid = threadIdx.x;
  const int blk = blockIdx.x;
  const int n = blk >> 8, h = (blk >> 6) & 3, k = blk & 63;
  if (tid < 192) {
    int jl = tid & 63;
    int chn = (tid < 64) ? k : ((tid < 128) ? ((k + 63) & 63) : ((k + 1) & 63));
    tmap[tid] = sidx[n * NHL + h * LLEN + chn * 64 + jl] & (LLEN - 1);
  }
  __syncthreads();
  const float* xen = xe + (size_t)n * LLEN * 64;
  const int il = tid & 63, jg = tid >> 6;
  float4 xi[16];
  float ml = -1e30f, sl = 0.f;
  for (int jc = 0; jc < 3; ++jc) {
    if (jc) __syncthreads();           // prev chunk's score reads of stg done
    {  // stage xtile rows tmap[jc*64 + r]
      int r = tid >> 2, c0 = (tid & 3) * 16;
      const float4* src = (const float4*)(xen + (size_t)tmap[jc * 64 + r] * 64 + c0);
      float4* dst = (float4*)&stg[r * 68 + c0];
      dst[0] = src[0]; dst[1] = src[1]; dst[2] = src[2]; dst[3] = src[3];
    }
    __syncthreads();
    {  // partial sum of squares (4 threads per row)
      int prt = tid >> 6;
      const float4* row = (const float4*)&stg[il * 68 + prt * 16];
      float s = 0.f;
#pragma unroll
      for (int u = 0; u < 4; ++u) {
        float4 vv = row[u];
        s += vv.x*vv.x + vv.y*vv.y + vv.z*vv.z + vv.w*vv.w;
      }
      psum[il * 4 + prt] = s;
    }
    __syncthreads();
    if (tid < 64) {
      float s = psum[tid*4] + psum[tid*4+1] + psum[tid*4+2] + psum[tid*4+3];
      rinv_c[tid] = 1.f / fmaxf(sqrtf(s), 5e-5f);
    }
    if (jc == 0) {   // query row il into registers (before stg gets recycled)
      const float4* xr = (const float4*)&stg[il * 68];
#pragma unroll
      for (int u = 0; u < 16; ++u) xi[u] = xr[u];
    }
    __syncthreads();
    // raw scores for this chunk: thread (il, jg) does j_local = jg*16 + jj
    for (int jj = 0; jj < 16; ++jj) {
      int jl2 = jg * 16 + jj;
      const float4* xj = (const float4*)&stg[jl2 * 68];   // broadcast across 64 lanes
      float4 d4 = make_float4(0, 0, 0, 0);
#pragma unroll
      for (int u = 0; u < 16; ++u) d4 = f4fma(xi[u], xj[u], d4);
      float d = (d4.x + d4.y + d4.z + d4.w) * rinv_c[jl2];
      score[il * 193 + jc * 64 + jl2] = d;
      if (d > ml) { sl = sl * __expf(ml - d) + 1.f; ml = d; }
      else sl += __expf(d - ml);
    }
  }
  // combine per-row lse over the 4 jg partials
  pm[il * 4 + jg] = ml; ps[il * 4 + jg] = sl;
  __syncthreads();
  if (tid < 64) {
    float m0 = pm[tid*4], m1 = pm[tid*4+1], m2 = pm[tid*4+2], m3 = pm[tid*4+3];
    float mm = fmaxf(fmaxf(m0, m1), fmaxf(m2, m3));
    float ss = ps[tid*4]  * __expf(m0 - mm) + ps[tid*4+1] * __expf(m1 - mm)
             + ps[tid*4+2] * __expf(m2 - mm) + ps[tid*4+3] * __expf(m3 - mm);
    float lv = mm + __logf(ss);
    lse_row[tid] = lv;
    lseg[n * NHL + h * LLEN + k * 64 + tid] = lv;
  }
  __syncthreads();
  {  // normalize own 48 raw scores in place: exp(raw - lse)
    float lv = lse_row[il];
#pragma unroll
    for (int jc = 0; jc < 3; ++jc)
      for (int jj = 0; jj < 16; ++jj) {
        int o = il * 193 + jc * 64 + jg * 16 + jj;
        score[o] = __expf(score[o] - lv);
      }
  }
  // PV: att[i][c] = sum_j score[i][j] * y[j][c]
  const int it = tid >> 5, cg = tid & 31;   // rows q*8+it, cols {4cg, 128+4cg}
  float4 a0[8], a1[8];
#pragma unroll
  for (int q = 0; q < 8; ++q) { a0[q] = make_float4(0,0,0,0); a1[q] = make_float4(0,0,0,0); }
  const float* yen = ye + (size_t)n * LLEN * 256;
  for (int yt = 0; yt < 12; ++yt) {
    __syncthreads();   // prev tile compute done (first iter: normalize done)
    {  // stage 16 y rows
      int r = tid >> 4, c0 = (tid & 15) * 16;
      const float4* src = (const float4*)(yen + (size_t)tmap[yt * 16 + r] * 256 + c0);
      float4* dst = (float4*)&stg[r * 260 + c0];
      dst[0] = src[0]; dst[1] = src[1]; dst[2] = src[2]; dst[3] = src[3];
    }
    __syncthreads();
    for (int jj = 0; jj < 16; ++jj) {
      int j = yt * 16 + jj;
      float4 y0 = *(const float4*)&stg[jj * 260 + 4 * cg];          // lane-consecutive f4: optimal
      float4 y1 = *(const float4*)&stg[jj * 260 + 128 + 4 * cg];
#pragma unroll
      for (int q = 0; q < 8; ++q) {
        float s = score[(q * 8 + it) * 193 + j];   // broadcast per half-wave
        a0[q] = f4fmas(s, y0, a0[q]);
        a1[q] = f4fmas(s, y1, a1[q]);
      }
    }
  }
  float* abase = att + ((size_t)n * NHL + h * LLEN + k * 64) * 256;
#pragma unroll
  for (int q = 0; q < 8; ++q) {
    int i = q * 8 + it;
    *(float4*)(abase + (size_t)i * 256 + 4 * cg) = a0[q];
    *(float4*)(abase + (size_t)i * 256 + 128 + 4 * cg) = a1[q];
  }
}

// ---------------- final: gather 4 head rows, head-softmax weights, BN3 + residual ----------------
__global__ __launch_bounds__(256) void k_final2(const float* __restrict__ att,
                                                const int* __restrict__ undo,
                                                const float* __restrict__ lse,
                                                const float* __restrict__ x,
                                                const float* __restrict__ g,
                                                const float* __restrict__ b,
                                                const float* __restrict__ m,
                                                const float* __restrict__ v,
                                                float* __restrict__ out) {
  __shared__ float t[64 * 257];
  __shared__ float wts[64 * 4];
  __shared__ int   pos[64 * 4];
  const int tid = threadIdx.x;
  const int n = blockIdx.x >> 6;
  const int l0 = (blockIdx.x & 63) << 6;
  if (tid < 64) {
    int l = l0 + tid;
    float e0 = lse[n * NHL + l];
    float e1 = lse[n * NHL + LLEN + l];
    float e2 = lse[n * NHL + 2 * LLEN + l];
    float e3 = lse[n * NHL + 3 * LLEN + l];
    float mx = fmaxf(fmaxf(e0, e1), fmaxf(e2, e3));
    float x0 = __expf(e0 - mx), x1 = __expf(e1 - mx), x2 = __expf(e2 - mx), x3 = __expf(e3 - mx);
    float inv = 1.f / (x0 + x1 + x2 + x3);
    wts[tid * 4 + 0] = x0 * inv; wts[tid * 4 + 1] = x1 * inv;
    wts[tid * 4 + 2] = x2 * inv; wts[tid * 4 + 3] = x3 * inv;
    pos[tid * 4 + 0] = undo[n * NHL + l];
    pos[tid * 4 + 1] = undo[n * NHL + LLEN + l];
    pos[tid * 4 + 2] = undo[n * NHL + 2 * LLEN + l];
    pos[tid * 4 + 3] = undo[n * NHL + 3 * LLEN + l];
  }
  __syncthreads();
  {
    const int ll = tid >> 2, part = tid & 3;   // 4 threads per l, 64 channels each
    float4 acc[16];
#pragma unroll
    for (int u = 0; u < 16; ++u) acc[u] = make_float4(0, 0, 0, 0);
    const float* an = att + (size_t)n * NHL * 256;
    for (int hh = 0; hh < 4; ++hh) {
      float wv = wts[ll * 4 + hh];
      const float4* row = (const float4*)(an + (size_t)pos[ll * 4 + hh] * 256 + part * 64);
#pragma unroll
      for (int u = 0; u < 16; ++u) acc[u] = f4fmas(wv, row[u], acc[u]);
    }
    float4* dst = (float4*)&t[ll * 257 + part * 64];
#pragma unroll
    for (int u = 0; u < 16; ++u) dst[u] = acc[u];
  }
  __syncthreads();
  for (int idx = tid; idx < 16384; idx += 256) {
    int c = idx >> 6, dl = idx & 63;
    float s = g[c] * rsqrtf(v[c] + 1e-5f);
    float bias = b[c] - m[c] * s;
    size_t o = ((size_t)n * 256 + c) * LLEN + l0 + dl;
    out[o] = t[dl * 257 + c] * s + bias + x[o];
  }
}

extern "C" void kernel_launch(void* const* d_in, const int* in_sizes, int n_in,
                              void* d_out, int out_size, void* d_ws, size_t ws_size,
                              hipStream_t stream) {
  const float* x       = (const float*)d_in[0];
  const float* rot     = (const float*)d_in[1];
  const float* w_match = (const float*)d_in[2];
  const float* bn1_g   = (const float*)d_in[3];
  const float* bn1_b   = (const float*)d_in[4];
  const float* bn1_m   = (const float*)d_in[5];
  const float* bn1_v   = (const float*)d_in[6];
  const float* w_asm   = (const float*)d_in[7];
  const float* bn2_g   = (const float*)d_in[8];
  const float* bn2_b   = (const float*)d_in[9];
  const float* bn2_m   = (const float*)d_in[10];
  const float* bn2_v   = (const float*)d_in[11];
  const float* bn3_g   = (const float*)d_in[12];
  const float* bn3_b   = (const float*)d_in[13];
  const float* bn3_m   = (const float*)d_in[14];
  const float* bn3_v   = (const float*)d_in[15];
  float* out = (float*)d_out;

  float* ws   = (float*)d_ws;
  float* xe   = ws;                      // [4][4096][64]    = 1,048,576 f
  float* ye   = xe + 1048576;            // [4][4096][256]   = 4,194,304 f
  float* att  = ye + 4194304;            // [4][16384][256]  = 16,777,216 f
  float* lse  = att + 16777216;          // [4][16384]       = 65,536 f
  int* codes  = (int*)(lse + 65536);     // [4][16384]
  int* sidx   = codes + 65536;           // [4][16384]
  int* undo   = sidx + 65536;            // [4][16384]
  int* offs   = undo + 65536;            // [4][68]
  // total ~89 MB of d_ws

  k_conv_match<<<256, 256, 0, stream>>>(x, w_match, bn1_g, bn1_b, bn1_m, bn1_v, xe);
  k_conv_asm<<<256, 256, 0, stream>>>(x, w_asm, bn2_g, bn2_b, bn2_m, bn2_v, ye);
  k_codes<<<256, 256, 0, stream>>>(xe, rot, codes);
  k_hist<<<NN, 256, 0, stream>>>(codes, offs);
  k_scatter<<<NN * NBINS, 64, 0, stream>>>(codes, offs, sidx, undo);
  k_att2<<<1024, 256, 0, stream>>>(xe, ye, sidx, lse, att);
  k_final2<<<NN * 64, 256, 0, stream>>>(att, undo, lse, x, bn3_g, bn3_b, bn3_m, bn3_v, out);
}

// Round 8
// 421.437 us; speedup vs baseline: 2.1841x; 1.1664x over previous
//
#include <hip/hip_runtime.h>
#include <math.h>

#define NN 4
#define CCH 256
#define LLEN 4096
#define NHEAD 4
#define NHL 16384      // NHEAD * LLEN
#define NBINS 67       // code values 0..66 (bucket 0..63 + head 0..3)

typedef __attribute__((ext_vector_type(8))) short bshort8;
typedef __attribute__((ext_vector_type(4))) float f32x4;

__device__ __forceinline__ float4 f4fma(float4 a, float4 b, float4 c) {
  c.x = fmaf(a.x, b.x, c.x);
  c.y = fmaf(a.y, b.y, c.y);
  c.z = fmaf(a.z, b.z, c.z);
  c.w = fmaf(a.w, b.w, c.w);
  return c;
}
__device__ __forceinline__ float4 f4fmas(float s, float4 b, float4 c) {
  c.x = fmaf(s, b.x, c.x);
  c.y = fmaf(s, b.y, c.y);
  c.z = fmaf(s, b.z, c.z);
  c.w = fmaf(s, b.w, c.w);
  return c;
}
__device__ __forceinline__ unsigned short f2bf(float f) {
  union { float f; unsigned u; } v; v.f = f;
  unsigned r = v.u + 0x7FFF + ((v.u >> 16) & 1);   // RNE
  return (unsigned short)(r >> 16);
}

// ---------------- conv_match: [N,C,L] -> BN1 -> ReLU -> xe [N,L,64] ----------------
// chunked x staging: 17.4 + 49.4 KB LDS -> 2 blocks/CU
__global__ __launch_bounds__(256, 2) void k_conv_match(
    const float* __restrict__ x, const float* __restrict__ w,
    const float* __restrict__ g, const float* __restrict__ b,
    const float* __restrict__ m, const float* __restrict__ v,
    float* __restrict__ xe) {
  __shared__ float xs[64 * 68];    // [ci_local][66 used, stride 68]
  __shared__ float wl[64 * 193];   // [co][192 used, stride 193]
  const int tid = threadIdx.x;
  const int n = blockIdx.x >> 6;
  const int l0 = (blockIdx.x & 63) << 6;
  const float* xn = x + (size_t)n * CCH * LLEN;
  const int co = tid & 63;
  const int dlg = tid >> 6;   // dl = dlg*16 + q
  float acc[16];
#pragma unroll
  for (int q = 0; q < 16; ++q) acc[q] = 0.f;
  for (int cc = 0; cc < 4; ++cc) {
    __syncthreads();   // prev chunk compute done
    for (int idx = tid; idx < 64 * 66; idx += 256) {
      int ci = idx / 66, j = idx - ci * 66;
      int l = l0 + j - 1;
      xs[ci * 68 + j] = (l >= 0 && l < LLEN) ? xn[(cc * 64 + ci) * LLEN + l] : 0.f;
    }
    for (int idx = tid; idx < 12288; idx += 256) {
      int cw = idx / 192, r = idx - cw * 192;
      wl[cw * 193 + r] = w[cw * 768 + cc * 192 + r];
    }
    __syncthreads();
    const float* wbase = &wl[co * 193];
    for (int cil = 0; cil < 64; ++cil) {
      const float* xrow = &xs[cil * 68 + dlg * 16];
      float4 p0 = ((const float4*)xrow)[0];
      float4 p1 = ((const float4*)xrow)[1];
      float4 p2 = ((const float4*)xrow)[2];
      float4 p3 = ((const float4*)xrow)[3];
      float4 p4 = ((const float4*)xrow)[4];
      float xr[20] = {p0.x,p0.y,p0.z,p0.w, p1.x,p1.y,p1.z,p1.w,
                      p2.x,p2.y,p2.z,p2.w, p3.x,p3.y,p3.z,p3.w,
                      p4.x,p4.y,p4.z,p4.w};
      float w0 = wbase[cil*3], w1 = wbase[cil*3+1], w2 = wbase[cil*3+2];
#pragma unroll
      for (int q = 0; q < 16; ++q) {
        acc[q] = fmaf(w0, xr[q], acc[q]);
        acc[q] = fmaf(w1, xr[q+1], acc[q]);
        acc[q] = fmaf(w2, xr[q+2], acc[q]);
      }
    }
  }
  float scale = g[co] * rsqrtf(v[co] + 1e-5f);
  float bias = b[co] - m[co] * scale;
  float* xo = xe + ((size_t)n * LLEN + l0) * 64 + co;
#pragma unroll
  for (int q = 0; q < 16; ++q) {
    float val = acc[q] * scale + bias;
    xo[(dlg * 16 + q) * 64] = val > 0.f ? val : 0.f;
  }
}

// ---------------- conv_asm (1x1): [N,C,L] -> BN2 -> ReLU -> ye [N,L,256] ----------------
// per-parity weight staging: 17.4 + 33.8 KB LDS -> 3 blocks/CU
__global__ __launch_bounds__(256, 3) void k_conv_asm(
    const float* __restrict__ x, const float* __restrict__ w,
    const float* __restrict__ g, const float* __restrict__ b,
    const float* __restrict__ m, const float* __restrict__ v,
    float* __restrict__ ye) {
  __shared__ float xt[64 * 68];    // [ci][l], stride 68
  __shared__ float wt[64 * 132];   // one parity at a time
  const int tid = threadIdx.x;
  const int n = blockIdx.x >> 6;
  const int l0 = (blockIdx.x & 63) << 6;
  const int cg = tid & 31, lt = tid >> 5;   // c0 = cg*8, l = l0 + lt*8 + q
  float4 a0[8], a1[8];
#pragma unroll
  for (int q = 0; q < 8; ++q) { a0[q] = make_float4(0,0,0,0); a1[q] = make_float4(0,0,0,0); }
  for (int cc = 0; cc < 4; ++cc) {
    __syncthreads();
    for (int idx = tid; idx < 4096; idx += 256) {
      int ci = idx >> 6, dl = idx & 63;
      xt[ci * 68 + dl] = x[((size_t)n * 256 + cc * 64 + ci) * 4096 + l0 + dl];
    }
    for (int idx = tid; idx < 8192; idx += 256) {      // parity 0: c = 8m + wq
      int ci = idx & 63, cl = idx >> 6;
      int c = ((cl >> 2) << 3) + (cl & 3);
      wt[ci * 132 + cl] = w[c * 256 + cc * 64 + ci];
    }
    __syncthreads();
    for (int ci = 0; ci < 64; ++ci) {
      const float4 xv0 = *(const float4*)&xt[ci * 68 + lt * 8];
      const float4 xv1 = *(const float4*)&xt[ci * 68 + lt * 8 + 4];
      const float4 w0 = *(const float4*)&wt[ci * 132 + cg * 4];   // c = 8cg..8cg+3
      float xl[8] = {xv0.x, xv0.y, xv0.z, xv0.w, xv1.x, xv1.y, xv1.z, xv1.w};
#pragma unroll
      for (int q = 0; q < 8; ++q) a0[q] = f4fmas(xl[q], w0, a0[q]);
    }
    __syncthreads();
    for (int idx = tid; idx < 8192; idx += 256) {      // parity 1: c = 8m + 4 + wq
      int ci = idx & 63, cl = idx >> 6;
      int c = ((cl >> 2) << 3) + 4 + (cl & 3);
      wt[ci * 132 + cl] = w[c * 256 + cc * 64 + ci];
    }
    __syncthreads();
    for (int ci = 0; ci < 64; ++ci) {
      const float4 xv0 = *(const float4*)&xt[ci * 68 + lt * 8];
      const float4 xv1 = *(const float4*)&xt[ci * 68 + lt * 8 + 4];
      const float4 w1 = *(const float4*)&wt[ci * 132 + cg * 4];   // c = 8cg+4..8cg+7
      float xl[8] = {xv0.x, xv0.y, xv0.z, xv0.w, xv1.x, xv1.y, xv1.z, xv1.w};
#pragma unroll
      for (int q = 0; q < 8; ++q) a1[q] = f4fmas(xl[q], w1, a1[q]);
    }
  }
  const int c0 = cg * 8;
  float sc[8], bs[8];
#pragma unroll
  for (int u = 0; u < 8; ++u) {
    float s = g[c0+u] * rsqrtf(v[c0+u] + 1e-5f);
    sc[u] = s; bs[u] = b[c0+u] - m[c0+u] * s;
  }
#pragma unroll
  for (int q = 0; q < 8; ++q) {
    int l = l0 + lt * 8 + q;
    float4 o0, o1;
    o0.x = fmaxf(a0[q].x*sc[0]+bs[0], 0.f);
    o0.y = fmaxf(a0[q].y*sc[1]+bs[1], 0.f);
    o0.z = fmaxf(a0[q].z*sc[2]+bs[2], 0.f);
    o0.w = fmaxf(a0[q].w*sc[3]+bs[3], 0.f);
    o1.x = fmaxf(a1[q].x*sc[4]+bs[4], 0.f);
    o1.y = fmaxf(a1[q].y*sc[5]+bs[5], 0.f);
    o1.z = fmaxf(a1[q].z*sc[6]+bs[6], 0.f);
    o1.w = fmaxf(a1[q].w*sc[7]+bs[7], 0.f);
    float4* dst = (float4*)(ye + ((size_t)n * LLEN + l) * 256 + c0);
    dst[0] = o0; dst[1] = o1;
  }
}

// ---------------- LSH codes ----------------
__global__ __launch_bounds__(256) void k_codes(
    const float* __restrict__ xe, const float* __restrict__ rot,
    int* __restrict__ codes) {
  __shared__ float xsh[64 * 65];
  const int tid = threadIdx.x;
  const int n = blockIdx.x >> 6;
  const int t0 = (blockIdx.x & 63) << 6;
  for (int idx = tid; idx < 4096; idx += 256) {
    int tt = idx >> 6, f = idx & 63;
    xsh[tt * 65 + f] = xe[((size_t)n * LLEN + t0 + tt) * 64 + f];
  }
  __syncthreads();
  const int tt = tid & 63, h = tid >> 6;
  float rvv[32];
#pragma unroll
  for (int i = 0; i < 32; ++i) rvv[i] = 0.f;
  const float* xr = &xsh[tt * 65];
  for (int f = 0; f < 64; ++f) {
    float xf = xr[f];
    const float* rr = rot + ((f << 2) + h) * 32;
#pragma unroll
    for (int i = 0; i < 32; ++i) rvv[i] = fmaf(xf, rr[i], rvv[i]);
  }
  float best = rvv[0]; int bi = 0;
#pragma unroll
  for (int i = 1; i < 32; ++i) { if (rvv[i] > best) { best = rvv[i]; bi = i; } }
#pragma unroll
  for (int i = 0; i < 32; ++i) { float nv = -rvv[i]; if (nv > best) { best = nv; bi = 32 + i; } }
  codes[n * NHL + h * LLEN + t0 + tt] = bi + h;
}

// ---------------- counting sort ----------------
__global__ __launch_bounds__(256) void k_hist(const int* __restrict__ codes,
                                              int* __restrict__ offs) {
  __shared__ int hist[NBINS];
  const int tid = threadIdx.x;
  const int n = blockIdx.x;
  if (tid < NBINS) hist[tid] = 0;
  __syncthreads();
  const int* cp = codes + n * NHL;
  for (int idx = tid; idx < NHL; idx += 256) atomicAdd(&hist[cp[idx]], 1);
  __syncthreads();
  if (tid == 0) {
    int s = 0;
    for (int c = 0; c < NBINS; ++c) { offs[n * (NBINS + 1) + c] = s; s += hist[c]; }
    offs[n * (NBINS + 1) + NBINS] = s;
  }
}

__global__ __launch_bounds__(64) void k_scatter(const int* __restrict__ codes,
                                                const int* __restrict__ offs,
                                                int* __restrict__ sidx,
                                                int* __restrict__ undo) {
  const int n = blockIdx.x / NBINS;
  const int c = blockIdx.x - n * NBINS;
  const int lane = threadIdx.x;
  const int* cp = codes + n * NHL;
  int base = offs[n * (NBINS + 1) + c];
  for (int ch = 0; ch < NHL / 64; ++ch) {
    int j = (ch << 6) + lane;
    int cv = cp[j];
    unsigned long long mk = __ballot(cv == c);
    if (cv == c) {
      int pos = base + __popcll(mk & ((1ull << lane) - 1ull));
      sidx[n * NHL + pos] = j;
      undo[n * NHL + j] = pos;
    }
    base += __popcll(mk);
  }
}

// ---------------- fused attention: f32 QK^T + lse, bf16 MFMA PV ----------------
__global__ __launch_bounds__(256, 2) void k_att2(const float* __restrict__ xe,
                                                 const float* __restrict__ ye,
                                                 const int* __restrict__ sidx,
                                                 float* __restrict__ lseg,
                                                 float* __restrict__ att) {
  __shared__ float score[64 * 193];   // f32 raw scores; first 25600B reused as bf16 P [64][200]
  __shared__ float stg[4608];         // xtile [64][68] f32 (QK) / yT bf16 [256][32] (PV)
  __shared__ int   tmap[192];
  __shared__ float rinv_c[64];
  __shared__ float psum[256];
  __shared__ float pm[256], ps[256];
  __shared__ float lse_row[64];
  const int tid = threadIdx.x;
  const int blk = blockIdx.x;
  const int n = blk >> 8, h = (blk >> 6) & 3, k = blk & 63;
  if (tid < 192) {
    int jl = tid & 63;
    int chn = (tid < 64) ? k : ((tid < 128) ? ((k + 63) & 63) : ((k + 1) & 63));
    tmap[tid] = sidx[n * NHL + h * LLEN + chn * 64 + jl] & (LLEN - 1);
  }
  __syncthreads();
  const float* xen = xe + (size_t)n * LLEN * 64;
  const int il = tid & 63, jg = tid >> 6;
  float4 xi[16];
  float ml = -1e30f, sl = 0.f;
  for (int jc = 0; jc < 3; ++jc) {
    if (jc) __syncthreads();
    {  // stage xtile rows tmap[jc*64 + r]
      int r = tid >> 2, c0 = (tid & 3) * 16;
      const float4* src = (const float4*)(xen + (size_t)tmap[jc * 64 + r] * 64 + c0);
      float4* dst = (float4*)&stg[r * 68 + c0];
      dst[0] = src[0]; dst[1] = src[1]; dst[2] = src[2]; dst[3] = src[3];
    }
    __syncthreads();
    {  // partial sum of squares
      int prt = tid >> 6;
      const float4* row = (const float4*)&stg[il * 68 + prt * 16];
      float s = 0.f;
#pragma unroll
      for (int u = 0; u < 4; ++u) {
        float4 vv = row[u];
        s += vv.x*vv.x + vv.y*vv.y + vv.z*vv.z + vv.w*vv.w;
      }
      psum[il * 4 + prt] = s;
    }
    __syncthreads();
    if (tid < 64) {
      float s = psum[tid*4] + psum[tid*4+1] + psum[tid*4+2] + psum[tid*4+3];
      rinv_c[tid] = 1.f / fmaxf(sqrtf(s), 5e-5f);
    }
    if (jc == 0) {
      const float4* xr = (const float4*)&stg[il * 68];
#pragma unroll
      for (int u = 0; u < 16; ++u) xi[u] = xr[u];
    }
    __syncthreads();
    for (int jj = 0; jj < 16; ++jj) {
      int jl2 = jg * 16 + jj;
      const float4* xj = (const float4*)&stg[jl2 * 68];
      float4 d4 = make_float4(0, 0, 0, 0);
#pragma unroll
      for (int u = 0; u < 16; ++u) d4 = f4fma(xi[u], xj[u], d4);
      float d = (d4.x + d4.y + d4.z + d4.w) * rinv_c[jl2];
      score[il * 193 + jc * 64 + jl2] = d;
      if (d > ml) { sl = sl * __expf(ml - d) + 1.f; ml = d; }
      else sl += __expf(d - ml);
    }
  }
  pm[il * 4 + jg] = ml; ps[il * 4 + jg] = sl;
  __syncthreads();
  if (tid < 64) {
    float m0 = pm[tid*4], m1 = pm[tid*4+1], m2 = pm[tid*4+2], m3 = pm[tid*4+3];
    float mm = fmaxf(fmaxf(m0, m1), fmaxf(m2, m3));
    float ss = ps[tid*4]  * __expf(m0 - mm) + ps[tid*4+1] * __expf(m1 - mm)
             + ps[tid*4+2] * __expf(m2 - mm) + ps[tid*4+3] * __expf(m3 - mm);
    float lv = mm + __logf(ss);
    lse_row[tid] = lv;
    lseg[n * NHL + h * LLEN + k * 64 + tid] = lv;
  }
  __syncthreads();
  // normalize: raw f32 -> regs -> (barrier) -> bf16 P in-place over the score buffer
  float pbuf[48];
  {
    float lv = lse_row[il];
#pragma unroll
    for (int jc2 = 0; jc2 < 3; ++jc2)
#pragma unroll
      for (int jj = 0; jj < 16; ++jj)
        pbuf[jc2 * 16 + jj] = __expf(score[il * 193 + jc2 * 64 + jg * 16 + jj] - lv);
  }
  __syncthreads();   // all raw-score reads complete before bf16 overwrite
  {
    unsigned short* sb = (unsigned short*)score;
#pragma unroll
    for (int jc2 = 0; jc2 < 3; ++jc2)
#pragma unroll
      for (int jj = 0; jj < 16; ++jj) {
        int j = jc2 * 64 + jg * 16 + jj;
        sb[il * 200 + j] = f2bf(pbuf[jc2 * 16 + jj]);
      }
  }
  // PV via MFMA: D[64][256] = P[64][192] x Y[192][256], K-chunks of 32
  const int wv = tid >> 6, l = tid & 63;
  f32x4 acc[16];
#pragma unroll
  for (int ct = 0; ct < 16; ++ct) acc[ct] = (f32x4){0.f, 0.f, 0.f, 0.f};
  const unsigned short* sb = (const unsigned short*)score;
  unsigned short* ysh = (unsigned short*)stg;
  const float* yen = ye + (size_t)n * LLEN * 256;
  for (int kk = 0; kk < 6; ++kk) {
    __syncthreads();   // prev chunk B-reads done; (kk=0) sb writes + xtile reads done
    {  // stage yT chunk: ysh[c][jl] = bf16(Y[kk*32+jl][c])
      int jl = tid & 31, c0 = (tid >> 5) * 32;
      const float4* src = (const float4*)(yen + (size_t)tmap[kk * 32 + jl] * 256 + c0);
#pragma unroll
      for (int u = 0; u < 8; ++u) {
        float4 yv = src[u];
        ysh[(c0 + u*4 + 0) * 32 + jl] = f2bf(yv.x);
        ysh[(c0 + u*4 + 1) * 32 + jl] = f2bf(yv.y);
        ysh[(c0 + u*4 + 2) * 32 + jl] = f2bf(yv.z);
        ysh[(c0 + u*4 + 3) * 32 + jl] = f2bf(yv.w);
      }
    }
    __syncthreads();
    // A frag: P rows 16*wv..+15, k-slice kk*32 + (l>>4)*8..+7  (row = l&15, k contiguous)
    bshort8 af = *(const bshort8*)&sb[(wv * 16 + (l & 15)) * 200 + kk * 32 + (l >> 4) * 8];
#pragma unroll
    for (int ct = 0; ct < 16; ++ct) {
      // B frag: col = ct*16 + (l&15), k = kk*32 + (l>>4)*8..+7 -> yT[col][k_local]
      bshort8 bf = *(const bshort8*)&ysh[(ct * 16 + (l & 15)) * 32 + (l >> 4) * 8];
      acc[ct] = __builtin_amdgcn_mfma_f32_16x16x32_bf16(af, bf, acc[ct], 0, 0, 0);
    }
  }
  float* abase = att + ((size_t)n * NHL + h * LLEN + k * 64) * 256;
#pragma unroll
  for (int ct = 0; ct < 16; ++ct) {
    int c = ct * 16 + (l & 15);
    int i0 = wv * 16 + (l >> 4) * 4;
#pragma unroll
    for (int r = 0; r < 4; ++r)
      abase[(size_t)(i0 + r) * 256 + c] = acc[ct][r];
  }
}

// ---------------- final: gather 4 head rows, head-softmax weights, BN3 + residual ----------------
// 32 l's per block -> 33 KB LDS -> 2 blocks/CU, grid 512
__global__ __launch_bounds__(256, 2) void k_final3(const float* __restrict__ att,
                                                   const int* __restrict__ undo,
                                                   const float* __restrict__ lse,
                                                   const float* __restrict__ x,
                                                   const float* __restrict__ g,
                                                   const float* __restrict__ b,
                                                   const float* __restrict__ m,
                                                   const float* __restrict__ v,
                                                   float* __restrict__ out) {
  __shared__ float t[32 * 257];
  __shared__ float wts[32 * 4];
  __shared__ int   pos[32 * 4];
  const int tid = threadIdx.x;
  const int n = blockIdx.x >> 7;
  const int l0 = (blockIdx.x & 127) << 5;
  if (tid < 32) {
    int l = l0 + tid;
    float e0 = lse[n * NHL + l];
    float e1 = lse[n * NHL + LLEN + l];
    float e2 = lse[n * NHL + 2 * LLEN + l];
    float e3 = lse[n * NHL + 3 * LLEN + l];
    float mx = fmaxf(fmaxf(e0, e1), fmaxf(e2, e3));
    float x0 = __expf(e0 - mx), x1 = __expf(e1 - mx), x2 = __expf(e2 - mx), x3 = __expf(e3 - mx);
    float inv = 1.f / (x0 + x1 + x2 + x3);
    wts[tid * 4 + 0] = x0 * inv; wts[tid * 4 + 1] = x1 * inv;
    wts[tid * 4 + 2] = x2 * inv; wts[tid * 4 + 3] = x3 * inv;
    pos[tid * 4 + 0] = undo[n * NHL + l];
    pos[tid * 4 + 1] = undo[n * NHL + LLEN + l];
    pos[tid * 4 + 2] = undo[n * NHL + 2 * LLEN + l];
    pos[tid * 4 + 3] = undo[n * NHL + 3 * LLEN + l];
  }
  __syncthreads();
  {
    const int ll = tid & 31, part = tid >> 5;   // 8 threads per l, 32 channels each
    float4 acc[8];
#pragma unroll
    for (int u = 0; u < 8; ++u) acc[u] = make_float4(0, 0, 0, 0);
    const float* an = att + (size_t)n * NHL * 256;
    for (int hh = 0; hh < 4; ++hh) {
      float wvv = wts[ll * 4 + hh];
      const float4* row = (const float4*)(an + (size_t)pos[ll * 4 + hh] * 256 + part * 32);
#pragma unroll
      for (int u = 0; u < 8; ++u) acc[u] = f4fmas(wvv, row[u], acc[u]);
    }
    float4* dst = (float4*)&t[ll * 257 + part * 32];
#pragma unroll
    for (int u = 0; u < 8; ++u) dst[u] = acc[u];
  }
  __syncthreads();
  for (int idx = tid; idx < 8192; idx += 256) {
    int c = idx >> 5, dl = idx & 31;
    float s = g[c] * rsqrtf(v[c] + 1e-5f);
    float bias = b[c] - m[c] * s;
    size_t o = ((size_t)n * 256 + c) * LLEN + l0 + dl;
    out[o] = t[dl * 257 + c] * s + bias + x[o];
  }
}

extern "C" void kernel_launch(void* const* d_in, const int* in_sizes, int n_in,
                              void* d_out, int out_size, void* d_ws, size_t ws_size,
                              hipStream_t stream) {
  const float* x       = (const float*)d_in[0];
  const float* rot     = (const float*)d_in[1];
  const float* w_match = (const float*)d_in[2];
  const float* bn1_g   = (const float*)d_in[3];
  const float* bn1_b   = (const float*)d_in[4];
  const float* bn1_m   = (const float*)d_in[5];
  const float* bn1_v   = (const float*)d_in[6];
  const float* w_asm   = (const float*)d_in[7];
  const float* bn2_g   = (const float*)d_in[8];
  const float* bn2_b   = (const float*)d_in[9];
  const float* bn2_m   = (const float*)d_in[10];
  const float* bn2_v   = (const float*)d_in[11];
  const float* bn3_g   = (const float*)d_in[12];
  const float* bn3_b   = (const float*)d_in[13];
  const float* bn3_m   = (const float*)d_in[14];
  const float* bn3_v   = (const float*)d_in[15];
  float* out = (float*)d_out;

  float* ws   = (float*)d_ws;
  float* xe   = ws;                      // [4][4096][64]    = 1,048,576 f
  float* ye   = xe + 1048576;            // [4][4096][256]   = 4,194,304 f
  float* att  = ye + 4194304;            // [4][16384][256]  = 16,777,216 f
  float* lse  = att + 16777216;          // [4][16384]       = 65,536 f
  int* codes  = (int*)(lse + 65536);     // [4][16384]
  int* sidx   = codes + 65536;           // [4][16384]
  int* undo   = sidx + 65536;            // [4][16384]
  int* offs   = undo + 65536;            // [4][68]

  k_conv_match<<<256, 256, 0, stream>>>(x, w_match, bn1_g, bn1_b, bn1_m, bn1_v, xe);
  k_conv_asm<<<256, 256, 0, stream>>>(x, w_asm, bn2_g, bn2_b, bn2_m, bn2_v, ye);
  k_codes<<<256, 256, 0, stream>>>(xe, rot, codes);
  k_hist<<<NN, 256, 0, stream>>>(codes, offs);
  k_scatter<<<NN * NBINS, 64, 0, stream>>>(codes, offs, sidx, undo);
  k_att2<<<1024, 256, 0, stream>>>(xe, ye, sidx, lse, att);
  k_final3<<<NN * 128, 256, 0, stream>>>(att, undo, lse, x, bn3_g, bn3_b, bn3_m, bn3_v, out);
}